// Round 7
// baseline (65.827 us; speedup 1.0000x reference)
//
#include <hip/hip_runtime.h>
#include <hip/hip_bf16.h>

// ProductLayer: B=4096, F=32, D=64, U=256
// out[:,   0:256] = lz       = E[B,2048] @ W1[2048,256]
// out[:, 256:512] = lp_inner = G[B,1024] @ V [1024,256]   (G_b = E_b E_b^T gram)
// out[:, 512:768] = lp_outer = M[B,4096] @ W2[4096,256]   (M rank-1 from FS, in-register)
// A = [E | G] bf16 [4096, 3072]; FS bf16 [4096,64]; Wt bf16 [256, 7168] (N-major)
// v7: full-K blocks (no split-K, no atomics, no zero kernel). BM=128 BN=64 BK=64,
// 384 blocks (seg0 / seg2-solo / seg1-backfill order), 48 KB LDS (3 blocks/CU),
// XOR-swizzled LDS, stage-first dbuf, plain stores. Preps merged into one kernel.

#define KA 3072
#define KW 7168

typedef __attribute__((ext_vector_type(8))) short short8v;
typedef __attribute__((ext_vector_type(4))) float f32x4;

#define GLOAD(src, dst) __builtin_amdgcn_global_load_lds( \
    (const __attribute__((address_space(1))) void*)(src), \
    (__attribute__((address_space(3))) void*)(dst), 16, 0, 0)

static __device__ __forceinline__ short f2bf(float f) {
    union { float f; unsigned u; } v; v.f = f;
    unsigned r = v.u + 0x7fffu + ((v.u >> 16) & 1u);  // RNE
    return (short)(r >> 16);
}
static __device__ __forceinline__ float bf2f(short s) {
    union { unsigned u; float f; } v; v.u = ((unsigned)(unsigned short)s) << 16;
    return v.f;
}
static __device__ __forceinline__ int cvtpk(float lo, float hi) {
    int r;
    asm("v_cvt_pk_bf16_f32 %0, %1, %2" : "=v"(r) : "v"(lo), "v"(hi));
    return r;
}

// ---------------- prep: blocks 0-4095 = prep_a rows; 4096-4351 = prep_w units ----
__global__ __launch_bounds__(256) void prep(const float* __restrict__ embeds,
                                            const float* __restrict__ lw,
                                            const float* __restrict__ iw,
                                            const float* __restrict__ ow,
                                            short* __restrict__ A,
                                            short* __restrict__ FS,
                                            short* __restrict__ Wt) {
    __shared__ float se[2048];
    __shared__ short sebf[2048];
    int t = threadIdx.x;

    if (blockIdx.x < 4096) {
        int b = blockIdx.x;
        const float* e = embeds + (size_t)b * 2048;
        short* arow = A + (size_t)b * KA;

        float4 v0 = ((const float4*)e)[t * 2];
        float4 v1 = ((const float4*)e)[t * 2 + 1];
        ((float4*)se)[t * 2] = v0;
        ((float4*)se)[t * 2 + 1] = v1;
        short8v sb;
        sb[0] = f2bf(v0.x); sb[1] = f2bf(v0.y); sb[2] = f2bf(v0.z); sb[3] = f2bf(v0.w);
        sb[4] = f2bf(v1.x); sb[5] = f2bf(v1.y); sb[6] = f2bf(v1.z); sb[7] = f2bf(v1.w);
        ((short8v*)sebf)[t] = sb;
        *(short8v*)&arow[t * 8] = sb;   // E segment [0, 2048)

        __syncthreads();
        if (t < 64) {
            float s = 0.f;
            #pragma unroll
            for (int f = 0; f < 32; ++f) s += se[f * 64 + t];
            FS[(size_t)b * 64 + t] = f2bf(s);
        }

        // G = E E^T via MFMA: 4 waves, one 16x16 tile each, K=64 in 2 steps
        int wid = t >> 6, lane = t & 63;
        int tm = wid >> 1, tn = wid & 1;
        int lr = lane & 15, lk = (lane >> 4) * 8;
        f32x4 g = {0.f, 0.f, 0.f, 0.f};
        #pragma unroll
        for (int ks = 0; ks < 2; ++ks) {
            short8v a  = *(const short8v*)&sebf[(tm * 16 + lr) * 64 + ks * 32 + lk];
            short8v bb = *(const short8v*)&sebf[(tn * 16 + lr) * 64 + ks * 32 + lk];
            g = __builtin_amdgcn_mfma_f32_16x16x32_bf16(a, bb, g, 0, 0, 0);
        }
        #pragma unroll
        for (int r = 0; r < 4; ++r) {
            int grow = tm * 16 + (lane >> 4) * 4 + r;
            int gcol = tn * 16 + lr;
            arow[2048 + grow * 32 + gcol] = f2bf(g[r]);  // G segment [2048, 3072)
        }
    } else {
        int u = blockIdx.x - 4096;
        short* w = Wt + (size_t)u * KW;

        for (int k = t; k < 2048; k += 256) w[k] = f2bf(lw[(size_t)k * 256 + u]);

        if (t < 32) se[t] = iw[u * 32 + t];
        __syncthreads();
        for (int idx = t; idx < 1024; idx += 256)
            w[2048 + idx] = f2bf(se[idx >> 5] * se[idx & 31]);

        const float* owu = ow + (size_t)u * 4096;
        for (int i = t; i < 512; i += 256) {
            float4 a = ((const float4*)owu)[i * 2];
            float4 b = ((const float4*)owu)[i * 2 + 1];
            short8v s;
            s[0] = f2bf(a.x); s[1] = f2bf(a.y); s[2] = f2bf(a.z); s[3] = f2bf(a.w);
            s[4] = f2bf(b.x); s[5] = f2bf(b.y); s[6] = f2bf(b.z); s[7] = f2bf(b.w);
            *(short8v*)&w[3072 + i * 8] = s;
        }
    }
}

// ---------------- GEMM v7: full-K, BM=128 BN=64 BK=64, 384 blocks ----------------
// ids 0-127: seg0 (32 it) -> CUs 0-127; 128-255: seg2 (64 it) -> CUs 128-255 solo;
// 256-383: seg1 (16 it) -> backfill CUs 0-127. Plain stores, no atomics.
__global__ __launch_bounds__(256) void gemm_tile(const short* __restrict__ A,
                                                 const short* __restrict__ Wt,
                                                 const short* __restrict__ FS,
                                                 float* __restrict__ out) {
    __shared__ short As[2][8192];    // 32 KB dbuf (seg2: As[0] = fs tile 128x64)
    __shared__ short Bs[2][4096];    // 16 KB dbuf

    int id = blockIdx.x;
    int seg, loc;
    if (id < 128)      { seg = 0; loc = id; }
    else if (id < 256) { seg = 2; loc = id - 128; }
    else               { seg = 1; loc = id - 256; }
    int mt = loc >> 2, nt = loc & 3;
    const int nk = (seg == 0) ? 32 : (seg == 1) ? 16 : 64;
    int brow = mt * 128, bcol = nt * 64;
    int akoff = (seg == 1) ? 2048 : 0;
    int boff  = (seg == 0) ? 0 : (seg == 1) ? 2048 : 3072;

    int t = threadIdx.x, w = t >> 6, lane = t & 63;
    int lr = lane & 15, hi = lane >> 4;
    int srow = t >> 3;                       // staging row 0..31 per issue
    int soct = (t & 7) ^ (srow & 7);         // pre-swizzled source octet (involution)

    const short* Asrc = A  + (size_t)(brow + srow) * KA + akoff + soct * 8;
    const short* Bsrc = Wt + (size_t)(bcol + srow) * KW + boff  + soct * 8;
    const short* Fsrc = FS + (size_t)(brow + srow) * 64 + soct * 8;

    auto stageA = [&](int p, int kt) {
        #pragma unroll
        for (int i = 0; i < 4; ++i)
            GLOAD(Asrc + (size_t)i * 32 * KA + kt * 64, &As[p][i * 2048 + t * 8]);
    };
    auto stageB = [&](int p, int kt) {
        #pragma unroll
        for (int i = 0; i < 2; ++i)
            GLOAD(Bsrc + (size_t)i * 32 * KW + kt * 64, &Bs[p][i * 2048 + t * 8]);
    };

    f32x4 acc[2][4];
    #pragma unroll
    for (int m = 0; m < 2; ++m)
        #pragma unroll
        for (int n = 0; n < 4; ++n) acc[m][n] = (f32x4){0.f, 0.f, 0.f, 0.f};

    if (seg == 2) {
        #pragma unroll
        for (int i = 0; i < 4; ++i)          // fs tile 128x64, staged once (swizzled)
            GLOAD(Fsrc + (size_t)i * 32 * 64, &As[0][i * 2048 + t * 8]);
        stageB(0, 0);
    } else {
        stageA(0, 0); stageB(0, 0);
    }
    __syncthreads();

    if (seg != 2) {
        for (int kt = 0; kt < nk; ++kt) {
            int cur = kt & 1;
            if (kt + 1 < nk) { stageA(cur ^ 1, kt + 1); stageB(cur ^ 1, kt + 1); }
            #pragma unroll
            for (int ks = 0; ks < 2; ++ks) {
                int oct = ((ks * 4 + hi) ^ (lr & 7)) * 8;   // swizzled read octet
                short8v a[2], b[4];
                #pragma unroll
                for (int m = 0; m < 2; ++m)
                    a[m] = *(const short8v*)&As[cur][(w * 32 + m * 16 + lr) * 64 + oct];
                #pragma unroll
                for (int n = 0; n < 4; ++n)
                    b[n] = *(const short8v*)&Bs[cur][(n * 16 + lr) * 64 + oct];
                #pragma unroll
                for (int m = 0; m < 2; ++m)
                    #pragma unroll
                    for (int n = 0; n < 4; ++n)
                        acc[m][n] = __builtin_amdgcn_mfma_f32_16x16x32_bf16(a[m], b[n], acc[m][n], 0, 0, 0);
            }
            __syncthreads();
        }
    } else {
        // preload the wave's fs j-octets (fixed per lane), f32
        float fj[2][2][8];
        #pragma unroll
        for (int m = 0; m < 2; ++m)
            #pragma unroll
            for (int ks = 0; ks < 2; ++ks) {
                int oct = ((ks * 4 + hi) ^ (lr & 7)) * 8;
                short8v v = *(const short8v*)&As[0][(w * 32 + m * 16 + lr) * 64 + oct];
                #pragma unroll
                for (int e = 0; e < 8; ++e) fj[m][ks][e] = bf2f(v[e]);
            }
        for (int kt = 0; kt < 64; ++kt) {
            int cur = kt & 1;
            if (kt + 1 < 64) stageB(cur ^ 1, kt + 1);
            int ioff = ((kt >> 3) ^ (lr & 7)) * 8 + (kt & 7);   // rank-1 col, swizzled
            float s[2];
            #pragma unroll
            for (int m = 0; m < 2; ++m)
                s[m] = bf2f(As[0][(w * 32 + m * 16 + lr) * 64 + ioff]);
            #pragma unroll
            for (int ks = 0; ks < 2; ++ks) {
                int oct = ((ks * 4 + hi) ^ (lr & 7)) * 8;
                short8v b[4];
                #pragma unroll
                for (int n = 0; n < 4; ++n)
                    b[n] = *(const short8v*)&Bs[cur][(n * 16 + lr) * 64 + oct];
                #pragma unroll
                for (int m = 0; m < 2; ++m) {
                    union { int i32[4]; short8v v; } fa;
                    #pragma unroll
                    for (int q = 0; q < 4; ++q)
                        fa.i32[q] = cvtpk(s[m] * fj[m][ks][2 * q], s[m] * fj[m][ks][2 * q + 1]);
                    #pragma unroll
                    for (int n = 0; n < 4; ++n)
                        acc[m][n] = __builtin_amdgcn_mfma_f32_16x16x32_bf16(fa.v, b[n], acc[m][n], 0, 0, 0);
                }
            }
            __syncthreads();
        }
    }

    int segbase = seg * 256;
    #pragma unroll
    for (int m = 0; m < 2; ++m) {
        int row0 = brow + w * 32 + m * 16 + hi * 4;
        #pragma unroll
        for (int n = 0; n < 4; ++n) {
            int col = segbase + bcol + n * 16 + lr;
            #pragma unroll
            for (int r = 0; r < 4; ++r)
                out[(size_t)(row0 + r) * 768 + col] = acc[m][n][r];
        }
    }
}

extern "C" void kernel_launch(void* const* d_in, const int* in_sizes, int n_in,
                              void* d_out, int out_size, void* d_ws, size_t ws_size,
                              hipStream_t stream) {
    const float* embeds = (const float*)d_in[0];
    const float* lw = (const float*)d_in[1];
    const float* iw = (const float*)d_in[2];
    const float* ow = (const float*)d_in[3];
    float* out = (float*)d_out;

    short* A  = (short*)d_ws;                    // 4096*3072*2 = 25,165,824 B
    short* Wt = A + (size_t)4096 * KA;           // + 256*7168*2 = 3,670,016 B
    short* FS = Wt + (size_t)256 * KW;           // + 4096*64*2 =    524,288 B

    prep<<<dim3(4352), dim3(256), 0, stream>>>(embeds, lw, iw, ow, A, FS, Wt);
    gemm_tile<<<dim3(384), dim3(256), 0, stream>>>(A, Wt, FS, out);
}

// Round 8
// 64.633 us; speedup vs baseline: 1.0185x; 1.0185x over previous
//
#include <hip/hip_runtime.h>
#include <hip/hip_bf16.h>

// ProductLayer: B=4096, F=32, D=64, U=256
// out[:,   0:256] = lz       = E[B,2048] @ W1[2048,256]
// out[:, 256:512] = lp_inner = G[B,1024] @ V [1024,256]   (G_b = E_b E_b^T gram)
// out[:, 512:768] = lp_outer = M[B,4096] @ W2[4096,256]   (M rank-1 from FS, in-register)
// A = [E | G] bf16 [4096, 3072]; FS bf16 [4096,64]; Wt bf16 [256, 7168] (N-major)
// v8: triple-buffered K-pipeline with COUNTED vmcnt (never drain to 0) + raw
// s_barrier + setprio around MFMA. XCD-aware block decode (each XCD: 16 blocks
// of each segment, contiguous mt-panels -> L2 A-reuse). BM=128 BN=64 BK=64.

#define KA 3072
#define KW 7168

typedef __attribute__((ext_vector_type(8))) short short8v;
typedef __attribute__((ext_vector_type(4))) float f32x4;

#define GLOAD(src, dst) __builtin_amdgcn_global_load_lds( \
    (const __attribute__((address_space(1))) void*)(src), \
    (__attribute__((address_space(3))) void*)(dst), 16, 0, 0)

static __device__ __forceinline__ short f2bf(float f) {
    union { float f; unsigned u; } v; v.f = f;
    unsigned r = v.u + 0x7fffu + ((v.u >> 16) & 1u);  // RNE
    return (short)(r >> 16);
}
static __device__ __forceinline__ float bf2f(short s) {
    union { unsigned u; float f; } v; v.u = ((unsigned)(unsigned short)s) << 16;
    return v.f;
}
static __device__ __forceinline__ int cvtpk(float lo, float hi) {
    int r;
    asm("v_cvt_pk_bf16_f32 %0, %1, %2" : "=v"(r) : "v"(lo), "v"(hi));
    return r;
}

// ---------------- prep: blocks 0-4095 = prep_a rows; 4096-4351 = prep_w units ----
__global__ __launch_bounds__(256) void prep(const float* __restrict__ embeds,
                                            const float* __restrict__ lw,
                                            const float* __restrict__ iw,
                                            const float* __restrict__ ow,
                                            short* __restrict__ A,
                                            short* __restrict__ FS,
                                            short* __restrict__ Wt) {
    __shared__ float se[2048];
    __shared__ short sebf[2048];
    int t = threadIdx.x;

    if (blockIdx.x < 4096) {
        int b = blockIdx.x;
        const float* e = embeds + (size_t)b * 2048;
        short* arow = A + (size_t)b * KA;

        float4 v0 = ((const float4*)e)[t * 2];
        float4 v1 = ((const float4*)e)[t * 2 + 1];
        ((float4*)se)[t * 2] = v0;
        ((float4*)se)[t * 2 + 1] = v1;
        short8v sb;
        sb[0] = f2bf(v0.x); sb[1] = f2bf(v0.y); sb[2] = f2bf(v0.z); sb[3] = f2bf(v0.w);
        sb[4] = f2bf(v1.x); sb[5] = f2bf(v1.y); sb[6] = f2bf(v1.z); sb[7] = f2bf(v1.w);
        ((short8v*)sebf)[t] = sb;
        *(short8v*)&arow[t * 8] = sb;   // E segment [0, 2048)

        __syncthreads();
        if (t < 64) {
            float s = 0.f;
            #pragma unroll
            for (int f = 0; f < 32; ++f) s += se[f * 64 + t];
            FS[(size_t)b * 64 + t] = f2bf(s);
        }

        // G = E E^T via MFMA: 4 waves, one 16x16 tile each, K=64 in 2 steps
        int wid = t >> 6, lane = t & 63;
        int tm = wid >> 1, tn = wid & 1;
        int lr = lane & 15, lk = (lane >> 4) * 8;
        f32x4 g = {0.f, 0.f, 0.f, 0.f};
        #pragma unroll
        for (int ks = 0; ks < 2; ++ks) {
            short8v a  = *(const short8v*)&sebf[(tm * 16 + lr) * 64 + ks * 32 + lk];
            short8v bb = *(const short8v*)&sebf[(tn * 16 + lr) * 64 + ks * 32 + lk];
            g = __builtin_amdgcn_mfma_f32_16x16x32_bf16(a, bb, g, 0, 0, 0);
        }
        #pragma unroll
        for (int r = 0; r < 4; ++r) {
            int grow = tm * 16 + (lane >> 4) * 4 + r;
            int gcol = tn * 16 + lr;
            arow[2048 + grow * 32 + gcol] = f2bf(g[r]);  // G segment [2048, 3072)
        }
    } else {
        int u = blockIdx.x - 4096;
        short* w = Wt + (size_t)u * KW;

        for (int k = t; k < 2048; k += 256) w[k] = f2bf(lw[(size_t)k * 256 + u]);

        if (t < 32) se[t] = iw[u * 32 + t];
        __syncthreads();
        for (int idx = t; idx < 1024; idx += 256)
            w[2048 + idx] = f2bf(se[idx >> 5] * se[idx & 31]);

        const float* owu = ow + (size_t)u * 4096;
        for (int i = t; i < 512; i += 256) {
            float4 a = ((const float4*)owu)[i * 2];
            float4 b = ((const float4*)owu)[i * 2 + 1];
            short8v s;
            s[0] = f2bf(a.x); s[1] = f2bf(a.y); s[2] = f2bf(a.z); s[3] = f2bf(a.w);
            s[4] = f2bf(b.x); s[5] = f2bf(b.y); s[6] = f2bf(b.z); s[7] = f2bf(b.w);
            *(short8v*)&w[3072 + i * 8] = s;
        }
    }
}

// ---------------- GEMM v8: triple-buffer, counted vmcnt, raw barriers ----------------
// Decode: xcd = id&7, slot = id>>3. slot 0-15: seg2, 16-31: seg0, 32-47: seg1.
// mt = xcd*4 + (q>>2), nt = q&3  -> each XCD owns 4 contiguous mt-panels per segment.
__global__ __launch_bounds__(256) void gemm_tile(const short* __restrict__ A,
                                                 const short* __restrict__ Wt,
                                                 const short* __restrict__ FS,
                                                 float* __restrict__ out) {
    __shared__ short As[3][8192];    // 48 KB (seg2: As[0] = fs tile 128x64)
    __shared__ short Bs[3][4096];    // 24 KB

    int id = blockIdx.x;
    int xcd = id & 7, slot = id >> 3, sgrp = slot >> 4, q = slot & 15;
    int seg = (sgrp == 0) ? 2 : (sgrp == 1) ? 0 : 1;
    int mt = xcd * 4 + (q >> 2), nt = q & 3;
    const int nk = (seg == 0) ? 32 : (seg == 1) ? 16 : 64;
    int brow = mt * 128, bcol = nt * 64;
    int akoff = (seg == 1) ? 2048 : 0;
    int boff  = (seg == 0) ? 0 : (seg == 1) ? 2048 : 3072;

    int t = threadIdx.x, w = t >> 6, lane = t & 63;
    int lr = lane & 15, hi = lane >> 4;
    int srow = t >> 3;                       // staging row 0..31 per issue
    int soct = (t & 7) ^ (srow & 7);         // pre-swizzled source octet (involution)

    const short* Asrc = A  + (size_t)(brow + srow) * KA + akoff + soct * 8;
    const short* Bsrc = Wt + (size_t)(bcol + srow) * KW + boff  + soct * 8;
    const short* Fsrc = FS + (size_t)(brow + srow) * 64 + soct * 8;

    auto stageA = [&](int p, int kt) {
        #pragma unroll
        for (int i = 0; i < 4; ++i)
            GLOAD(Asrc + (size_t)i * 32 * KA + kt * 64, &As[p][i * 2048 + t * 8]);
    };
    auto stageB = [&](int p, int kt) {
        #pragma unroll
        for (int i = 0; i < 2; ++i)
            GLOAD(Bsrc + (size_t)i * 32 * KW + kt * 64, &Bs[p][i * 2048 + t * 8]);
    };

    f32x4 acc[2][4];
    #pragma unroll
    for (int m = 0; m < 2; ++m)
        #pragma unroll
        for (int n = 0; n < 4; ++n) acc[m][n] = (f32x4){0.f, 0.f, 0.f, 0.f};

    auto compute = [&](const short* a_s, const short* b_s) {
        #pragma unroll
        for (int ks = 0; ks < 2; ++ks) {
            int oct = ((ks * 4 + hi) ^ (lr & 7)) * 8;   // swizzled read octet
            short8v a[2], b[4];
            #pragma unroll
            for (int m = 0; m < 2; ++m)
                a[m] = *(const short8v*)&a_s[(w * 32 + m * 16 + lr) * 64 + oct];
            #pragma unroll
            for (int n = 0; n < 4; ++n)
                b[n] = *(const short8v*)&b_s[(n * 16 + lr) * 64 + oct];
            __builtin_amdgcn_s_setprio(1);
            #pragma unroll
            for (int m = 0; m < 2; ++m)
                #pragma unroll
                for (int n = 0; n < 4; ++n)
                    acc[m][n] = __builtin_amdgcn_mfma_f32_16x16x32_bf16(a[m], b[n], acc[m][n], 0, 0, 0);
            __builtin_amdgcn_s_setprio(0);
        }
    };

    if (seg != 2) {
        stageA(0, 0); stageB(0, 0);
        stageA(1, 1); stageB(1, 1);
        stageA(2, 2); stageB(2, 2);           // 18 loads in flight
        __builtin_amdgcn_sched_barrier(0);
        for (int kt = 0; kt < nk; ++kt) {
            int cur = kt % 3;
            if (kt + 2 < nk)      asm volatile("s_waitcnt vmcnt(12)" ::: "memory");
            else if (kt + 1 < nk) asm volatile("s_waitcnt vmcnt(6)" ::: "memory");
            else                  asm volatile("s_waitcnt vmcnt(0)" ::: "memory");
            __builtin_amdgcn_s_barrier();          // all waves' stage-kt landed
            __builtin_amdgcn_sched_barrier(0);
            compute(As[cur], Bs[cur]);
            __builtin_amdgcn_sched_barrier(0);
            __builtin_amdgcn_s_barrier();          // all waves done reading buf cur
            if (kt + 3 < nk) { stageA(cur, kt + 3); stageB(cur, kt + 3); }
            __builtin_amdgcn_sched_barrier(0);
        }
    } else {
        #pragma unroll
        for (int i = 0; i < 4; ++i)          // fs tile 128x64 -> As[0] (swizzled), once
            GLOAD(Fsrc + (size_t)i * 32 * 64, &As[0][i * 2048 + t * 8]);
        stageB(0, 0); stageB(1, 1); stageB(2, 2);   // 4 + 6 loads in flight
        asm volatile("s_waitcnt vmcnt(6)" ::: "memory");   // fs landed
        __builtin_amdgcn_s_barrier();
        __builtin_amdgcn_sched_barrier(0);

        // preload the wave's fs j-octets (fixed per lane), f32
        float fj[2][2][8];
        #pragma unroll
        for (int m = 0; m < 2; ++m)
            #pragma unroll
            for (int ks = 0; ks < 2; ++ks) {
                int oct = ((ks * 4 + hi) ^ (lr & 7)) * 8;
                short8v v = *(const short8v*)&As[0][(w * 32 + m * 16 + lr) * 64 + oct];
                #pragma unroll
                for (int e = 0; e < 8; ++e) fj[m][ks][e] = bf2f(v[e]);
            }
        for (int kt = 0; kt < 64; ++kt) {
            int cur = kt % 3;
            if (kt + 2 < 64)      asm volatile("s_waitcnt vmcnt(4)" ::: "memory");
            else if (kt + 1 < 64) asm volatile("s_waitcnt vmcnt(2)" ::: "memory");
            else                  asm volatile("s_waitcnt vmcnt(0)" ::: "memory");
            __builtin_amdgcn_s_barrier();
            __builtin_amdgcn_sched_barrier(0);
            int ioff = ((kt >> 3) ^ (lr & 7)) * 8 + (kt & 7);   // rank-1 col, swizzled
            float s[2];
            #pragma unroll
            for (int m = 0; m < 2; ++m)
                s[m] = bf2f(As[0][(w * 32 + m * 16 + lr) * 64 + ioff]);
            #pragma unroll
            for (int ks = 0; ks < 2; ++ks) {
                int oct = ((ks * 4 + hi) ^ (lr & 7)) * 8;
                short8v b[4];
                #pragma unroll
                for (int n = 0; n < 4; ++n)
                    b[n] = *(const short8v*)&Bs[cur][(n * 16 + lr) * 64 + oct];
                #pragma unroll
                for (int m = 0; m < 2; ++m) {
                    union { int i32[4]; short8v v; } fa;
                    #pragma unroll
                    for (int q2 = 0; q2 < 4; ++q2)
                        fa.i32[q2] = cvtpk(s[m] * fj[m][ks][2 * q2], s[m] * fj[m][ks][2 * q2 + 1]);
                    __builtin_amdgcn_s_setprio(1);
                    #pragma unroll
                    for (int n = 0; n < 4; ++n)
                        acc[m][n] = __builtin_amdgcn_mfma_f32_16x16x32_bf16(fa.v, b[n], acc[m][n], 0, 0, 0);
                    __builtin_amdgcn_s_setprio(0);
                }
            }
            __builtin_amdgcn_sched_barrier(0);
            __builtin_amdgcn_s_barrier();          // all waves done with Bs[cur]
            if (kt + 3 < 64) stageB(cur, kt + 3);
            __builtin_amdgcn_sched_barrier(0);
        }
    }

    int segbase = seg * 256;
    #pragma unroll
    for (int m = 0; m < 2; ++m) {
        int row0 = brow + w * 32 + m * 16 + hi * 4;
        #pragma unroll
        for (int n = 0; n < 4; ++n) {
            int col = segbase + bcol + n * 16 + lr;
            #pragma unroll
            for (int r = 0; r < 4; ++r)
                out[(size_t)(row0 + r) * 768 + col] = acc[m][n][r];
        }
    }
}

extern "C" void kernel_launch(void* const* d_in, const int* in_sizes, int n_in,
                              void* d_out, int out_size, void* d_ws, size_t ws_size,
                              hipStream_t stream) {
    const float* embeds = (const float*)d_in[0];
    const float* lw = (const float*)d_in[1];
    const float* iw = (const float*)d_in[2];
    const float* ow = (const float*)d_in[3];
    float* out = (float*)d_out;

    short* A  = (short*)d_ws;                    // 4096*3072*2 = 25,165,824 B
    short* Wt = A + (size_t)4096 * KA;           // + 256*7168*2 = 3,670,016 B
    short* FS = Wt + (size_t)256 * KW;           // + 4096*64*2 =    524,288 B

    prep<<<dim3(4352), dim3(256), 0, stream>>>(embeds, lw, iw, ow, A, FS, Wt);
    gemm_tile<<<dim3(384), dim3(256), 0, stream>>>(A, Wt, FS, out);
}